// Round 9
// baseline (138.804 us; speedup 1.0000x reference)
//
#include <hip/hip_runtime.h>
#include <hip/hip_bf16.h>

// EdgeDecoder: out[e] = W2 @ relu(W1 @ [z[src]; z[dst]] + b1) + b2
// Restructure: W1 = [W1a | W1b] over the concat ->
//   U[n] = W1a @ z[n] (+b1 folded), V[n] = W1b @ z[n]  (3.28 GFLOP via MFMA)
//   out[e] = dot(relu(U'[src] + V[dst]), W2) + b2
//
// R9 (= R8 theory, compile-fixed): fp16 U/V + packed-f16 phase-2 math via
// native _Float16 ext-vectors (__builtin_elementwise_*) — ROCm 7.2's
// bf16+fp16 headers have mutually broken __h*2 overload sets, so named
// intrinsics are avoided entirely. Per-2-elem math: pk_add -> pk_max ->
// pk_fma (was ~12 scalar VALU ops).
// Phase 1 unchanged from R7: global_load_lds DMA staging (no VGPR pressure),
// LDS bf16 convert, MFMA, LDS-transposed coalesced epilogue.

#define N_NODES 50000
#define N_EDGES 640000
#define H 128

using bf16 = __hip_bfloat16;
typedef __attribute__((ext_vector_type(8))) short short8;     // 8x16b, 4 VGPRs
typedef __attribute__((ext_vector_type(4))) float f32x4;      // MFMA acc
typedef __attribute__((ext_vector_type(2))) _Float16 h2v;     // packed f16

#define GLD_LDS16(g, l)                                                     \
  __builtin_amdgcn_global_load_lds(                                         \
      (const __attribute__((address_space(1))) void*)(g),                   \
      (__attribute__((address_space(3))) void*)(l), 16, 0, 0)

static __device__ __forceinline__ short bfbits(float x) {
  __hip_bfloat16 h = __float2bfloat16(x);
  return *reinterpret_cast<short*>(&h);
}

static __device__ __forceinline__ unsigned short h16(float x) {
  union { _Float16 h; unsigned short u; } c;
  c.h = (_Float16)x;  // RNE, same as __float2half_rn
  return c.u;
}

static __device__ __forceinline__ h2v h2(unsigned u) {
  union { unsigned u; h2v h; } c; c.u = u; return c.h;
}

static __device__ __forceinline__ short8 pack8(float4 a, float4 b) {
  short8 r;
  r[0] = bfbits(a.x); r[1] = bfbits(a.y); r[2] = bfbits(a.z); r[3] = bfbits(a.w);
  r[4] = bfbits(b.x); r[5] = bfbits(b.y); r[6] = bfbits(b.z); r[7] = bfbits(b.w);
  return r;
}

// Tiny: Wb[o][k] (bf16, A-frag row layout) from fp32 W1. o<128 -> W1[o][k],
// o>=128 -> W1[o-128][128+k]. 4096 units of 8 elems -> 16 blocks.
__global__ __launch_bounds__(256) void w_to_bf16(const float* __restrict__ W1,
                                                 bf16* __restrict__ Wb) {
  const int u = blockIdx.x * 256 + threadIdx.x;
  const int o = u >> 4, k8 = (u & 15) * 8;
  const float4* src = reinterpret_cast<const float4*>(
      W1 + (size_t)(o & (H - 1)) * (2 * H) + (o >> 7) * H + k8);
  *reinterpret_cast<short8*>(Wb + (size_t)o * H + k8) = pack8(src[0], src[1]);
}

#define HP 136  // padded bf16 LDS row stride: breaks 256B-stride conflicts

// Phase 1: block = 4 waves = one 32-node tile; wave s owns outputs
// [s*64, s*64+64). fp32 z staged via global_load_lds DMA (no VGPRs), one
// LDS pass converts to bf16 tile, frags via ds_read_b128, 32 MFMAs, then
// LDS-transposed coalesced epilogue writes U (+bias1, fp16) and V (fp16).
__global__ __launch_bounds__(256) void precompute_uv(
    const float* __restrict__ z, const bf16* __restrict__ Wb,
    const float* __restrict__ bias1,
    _Float16* __restrict__ U, _Float16* __restrict__ V) {
  __shared__ float ldsF[32 * H];       // 16 KB: fp32 z stage, later epilogue tile
  __shared__ bf16 ldsH[32 * HP];       // 8.5 KB: padded bf16 z tile
  const int tid = threadIdx.x;
  const int lane = tid & 63;
  const int s = tid >> 6;  // wave id = o-split 0..3
  const int l15 = lane & 15, quad = lane >> 4;
  const int nodebase = blockIdx.x * 32;

  // Stage: wave s DMAs rows [s*8, s*8+8) of the tile; 4 x 1KB contiguous.
  {
    int r0 = nodebase + s * 8;
    if (r0 > N_NODES - 8) r0 = N_NODES - 8;  // tail clamp (stores guarded)
    const float* gsrc = z + (size_t)r0 * H + lane * 4;
    float* ldst = ldsF + s * 8 * H;  // + lane*16B implicit
#pragma unroll
    for (int j = 0; j < 4; ++j) GLD_LDS16(gsrc + j * 256, ldst + j * 256);
  }

  // W-frags from global bf16 (64 KB, L2-hot) — overlaps the DMA.
  short8 wf[4][4];  // [o-tile][k-step]
#pragma unroll
  for (int t = 0; t < 4; ++t) {
    const bf16* wp = Wb + (size_t)(s * 64 + t * 16 + l15) * H + quad * 8;
#pragma unroll
    for (int q = 0; q < 4; ++q)
      wf[t][q] = *reinterpret_cast<const short8*>(wp + q * 32);
  }

  __syncthreads();  // DMA + conversion-input visible

  // Convert: thread handles 16 consecutive fp32 of row (tid>>3).
  {
    const int row = tid >> 3, off = (tid & 7) * 16;
    const float4* fp = reinterpret_cast<const float4*>(ldsF + row * H + off);
    const float4 a = fp[0], b = fp[1], c = fp[2], d = fp[3];
    *reinterpret_cast<short8*>(&ldsH[row * HP + off]) = pack8(a, b);
    *reinterpret_cast<short8*>(&ldsH[row * HP + off + 8]) = pack8(c, d);
  }
  __syncthreads();

  // z-frags from LDS + 32 back-to-back MFMAs.
  short8 zf[2][4];
#pragma unroll
  for (int m = 0; m < 2; ++m)
#pragma unroll
    for (int q = 0; q < 4; ++q)
      zf[m][q] = *reinterpret_cast<const short8*>(
          &ldsH[(m * 16 + l15) * HP + quad * 8 + q * 32]);

  f32x4 acc[2][4] = {};
#pragma unroll
  for (int m = 0; m < 2; ++m)
#pragma unroll
    for (int t = 0; t < 4; ++t)
#pragma unroll
      for (int q = 0; q < 4; ++q)
        acc[m][t] =
            __builtin_amdgcn_mfma_f32_16x16x32_bf16(wf[t][q], zf[m][q], acc[m][t], 0, 0, 0);

  // Epilogue 1: acc (+bias1 for the U half) -> LDS as fp16. C/D layout:
  // col=l15 -> node row nl, row=quad*4+reg -> output o. Waves 0,1 own U
  // outputs (o<128, add b1); waves 2,3 own V outputs.
  float4 b1v[4];
#pragma unroll
  for (int t = 0; t < 4; ++t)
    b1v[t] = (s < 2)
                 ? *reinterpret_cast<const float4*>(bias1 + s * 64 + t * 16 + quad * 4)
                 : make_float4(0.f, 0.f, 0.f, 0.f);

  _Float16* epi = reinterpret_cast<_Float16*>(ldsF);
#pragma unroll
  for (int m = 0; m < 2; ++m) {
    const int nl = m * 16 + l15;
#pragma unroll
    for (int t = 0; t < 4; ++t) {
      const int o = s * 64 + t * 16 + quad * 4;
      ushort4 st;
      st.x = h16(acc[m][t][0] + b1v[t].x);
      st.y = h16(acc[m][t][1] + b1v[t].y);
      st.z = h16(acc[m][t][2] + b1v[t].z);
      st.w = h16(acc[m][t][3] + b1v[t].w);
      *reinterpret_cast<ushort4*>(epi + nl * 256 + o) = st;
    }
  }
  __syncthreads();

  // Epilogue 2: coalesced stores; each instr = 4 node-rows x 256B contiguous.
#pragma unroll
  for (int half = 0; half < 2; ++half) {
    _Float16* base = half ? V : U;
#pragma unroll
    for (int it = 0; it < 2; ++it) {
      const int nl = s * 8 + it * 4 + (lane >> 4);
      const int oc = (lane & 15) * 8;
      const short8 v = *reinterpret_cast<const short8*>(epi + nl * 256 + half * H + oc);
      const int n = nodebase + nl;
      if (n < N_NODES)
        *reinterpret_cast<short8*>(base + (size_t)n * H + oc) = v;
    }
  }
}

static __device__ __forceinline__ h2v relu_fma(unsigned u, unsigned v,
                                               h2v w2, h2v acc) {
  const h2v h = __builtin_elementwise_max(h2(u) + h2(v), (h2v)(_Float16)0);
  return __builtin_elementwise_fma(h, w2, acc);
}

// Phase 2: one wave per 64-edge chunk. 8-lane group per edge; lane owns 16
// hidden elems = 2x16B U loads + 2x16B V loads, batched 4 edges deep.
// Inner math packed f16: pk_add (b1 pre-folded) -> pk_max -> pk_fma.
__global__ __launch_bounds__(256, 4) void edge_decode(
    const int* __restrict__ eidx, const _Float16* __restrict__ Ub,
    const _Float16* __restrict__ Vb, const float* __restrict__ W2,
    const float* __restrict__ bias2, float* __restrict__ out) {
  const int lane = threadIdx.x & 63;
  const int w = blockIdx.x * 4 + (int)(threadIdx.x >> 6);
  const int chunk = w * 64;
  const int e8 = lane & 7;

  h2v w2h[8];
  const float4* wp = reinterpret_cast<const float4*>(W2 + e8 * 16);
#pragma unroll
  for (int q = 0; q < 4; ++q) {
    const float4 wv = wp[q];
    w2h[2 * q][0] = (_Float16)wv.x; w2h[2 * q][1] = (_Float16)wv.y;
    w2h[2 * q + 1][0] = (_Float16)wv.z; w2h[2 * q + 1][1] = (_Float16)wv.w;
  }
  const float b2 = bias2[0];

  const int src = eidx[chunk + lane];
  const int dst = eidx[N_EDGES + chunk + lane];
  const uint4* U4 = reinterpret_cast<const uint4*>(Ub);  // row = 16 uint4
  const uint4* V4 = reinterpret_cast<const uint4*>(Vb);

  float res = 0.f;
#pragma unroll
  for (int hb = 0; hb < 2; ++hb) {
    uint4 ua[4], ub[4], va[4], vb[4];
    // Issue all 16 gather loads for 4 edges before any compute.
#pragma unroll
    for (int j = 0; j < 4; ++j) {
      const int i = hb * 4 + j;
      const int sl = (lane & 56) + i;
      const int s_i = __shfl(src, sl);
      const int d_i = __shfl(dst, sl);
      const uint4* up = U4 + (size_t)s_i * 16 + e8 * 2;
      const uint4* vp = V4 + (size_t)d_i * 16 + e8 * 2;
      ua[j] = up[0]; ub[j] = up[1];
      va[j] = vp[0]; vb[j] = vp[1];
    }
#pragma unroll
    for (int j = 0; j < 4; ++j) {
      const int i = hb * 4 + j;
      h2v acc = (h2v)(_Float16)0;
      acc = relu_fma(ua[j].x, va[j].x, w2h[0], acc);
      acc = relu_fma(ua[j].y, va[j].y, w2h[1], acc);
      acc = relu_fma(ua[j].z, va[j].z, w2h[2], acc);
      acc = relu_fma(ua[j].w, va[j].w, w2h[3], acc);
      acc = relu_fma(ub[j].x, vb[j].x, w2h[4], acc);
      acc = relu_fma(ub[j].y, vb[j].y, w2h[5], acc);
      acc = relu_fma(ub[j].z, vb[j].z, w2h[6], acc);
      acc = relu_fma(ub[j].w, vb[j].w, w2h[7], acc);
      float sum = (float)acc[0] + (float)acc[1];
      sum += __shfl_xor(sum, 1);
      sum += __shfl_xor(sum, 2);
      sum += __shfl_xor(sum, 4);
      if (e8 == i) res = sum + b2;
    }
  }
  out[chunk + lane] = res;  // coalesced 4 B/lane
}

extern "C" void kernel_launch(void* const* d_in, const int* in_sizes, int n_in,
                              void* d_out, int out_size, void* d_ws, size_t ws_size,
                              hipStream_t stream) {
  const float* z     = (const float*)d_in[0];
  const float* W1    = (const float*)d_in[1];
  const float* bias1 = (const float*)d_in[2];
  const float* W2    = (const float*)d_in[3];
  const float* bias2 = (const float*)d_in[4];
  const int*   eidx  = (const int*)d_in[5];
  float* out = (float*)d_out;

  _Float16* U  = (_Float16*)d_ws;            // [N_NODES, H] fp16 (bias1 folded)
  _Float16* V  = U + (size_t)N_NODES * H;    // [N_NODES, H] fp16
  bf16*     Wb = (bf16*)(V + (size_t)N_NODES * H);  // [256, H] bf16 (64 KB)

  // W convert: 4096 units / 256 = 16 blocks (~1.5 us).
  hipLaunchKernelGGL(w_to_bf16, dim3(16), dim3(256), 0, stream, W1, Wb);
  // Phase 1: 1563 blocks x 4 waves; block = 32-node tile, wave = 64-output split.
  hipLaunchKernelGGL(precompute_uv, dim3((N_NODES + 31) / 32), dim3(256), 0, stream,
                     z, Wb, bias1, U, V);
  // Phase 2: 10000 waves, one 64-edge chunk each.
  hipLaunchKernelGGL(edge_decode, dim3(N_EDGES / 64 / 4), dim3(256), 0, stream,
                     eidx, U, V, W2, bias2, out);
}